// Round 4
// baseline (422.518 us; speedup 1.0000x reference)
//
#include <hip/hip_runtime.h>
#include <math.h>

#define SQ2G 4.42718872424f   // sqrtf(19.6f)

__device__ __forceinline__ float wave_sum(float v) {
#pragma unroll
    for (int o = 32; o > 0; o >>= 1) v += __shfl_xor(v, o);
    return v;
}

// Drain one bucket's 1024 spigots (minus spigot 0, handled by caller).
// e[c] = H - h per lane, cc[c] = theta*a*sqrt(2G). cum is in/out.
// qmine[c] receives this lane's spigot flow for chunk c (0 if none).
// Ballot ONCE per chunk at entry (superset; excluded spigots have q==0 exactly
// since u only decreases; included spigots gated on d>0 which reproduces the
// reference's max(0,.)). Next candidate's (e,c) shfl is issued before the
// current sqrt chain -> software-pipelined, bpermute latency hidden.
template<int FIRST_AVAIL>
__device__ __forceinline__ void drain(const float* e, const float* cc, int lane,
                                      float& cum, float* qmine)
{
#pragma unroll
    for (int c = 0; c < 16; ++c) {
        float hc = 0.5f * cum;
        unsigned long long cand = __ballot(e[c] > hc);
        if (c == 0 && FIRST_AVAIL) cand &= ~1ull;
        float qm = 0.0f;
        if (cand) {
            int j = __builtin_ctzll(cand); cand &= cand - 1;
            float ej = __shfl(e[c], j);
            float cj = __shfl(cc[c], j);
            while (true) {
                bool more = (cand != 0);
                int jn = 0; float en = 0.0f, cn = 0.0f;
                if (more) {
                    jn = __builtin_ctzll(cand); cand &= cand - 1;
                    en = __shfl(e[c], jn);      // issued before sqrt chain below
                    cn = __shfl(cc[c], jn);
                }
                float d = fmaf(-0.5f, cum, ej);
                float q = (d > 0.0f) ? cj * sqrtf(d) : 0.0f;
                cum += q;
                if (lane == j) qm = q;
                if (!more) break;
                j = jn; ej = en; cj = cn;
            }
        }
        qmine[c] = qm;
    }
}

// ---------------- Layer 0: single head bucket, 1024 spigots. One wave. ----------------
// Writes q0[i] into P layout [dest_block][src=0][w]: P[(i>>2)*1024 + (i&3)].
__global__ __launch_bounds__(64)
void layer0_kernel(const float* __restrict__ H0p, const float* __restrict__ S0,
                   const float* __restrict__ theta0, const float* __restrict__ precip,
                   float* __restrict__ out, float* __restrict__ P0)
{
    const int lane = threadIdx.x;
    const float H  = H0p[0];
    const float pl = precip[0] * 0.0625f;          // precip / 16 (exact)

    const float2* S2 = (const float2*)S0;
    float e[16], cc[16];
#pragma unroll
    for (int c = 0; c < 16; ++c) {
        float2 s = S2[c * 64 + lane];
        float t  = theta0[c * 64 + lane];
        e[c]  = H - s.x;
        cc[c] = t * s.y * SQ2G;
    }

    // spigot 0: H_eff = H + inflow
    float e0 = __shfl(e[0], 0), c0 = __shfl(cc[0], 0);
    float d0 = e0 + pl;
    float q0 = (d0 > 0.0f) ? c0 * sqrtf(d0) : 0.0f;
    float cum = q0;

    float qmine[16];
    drain<1>(e, cc, lane, cum, qmine);

#pragma unroll
    for (int c = 0; c < 16; ++c) {
        int i = c * 64 + lane;
        float q = (i == 0) ? q0 : qmine[c];
        P0[(i >> 2) * 1024 + (i & 3)] = q;
    }
    if (lane == 0) out[0] = (H - cum) + pl;        // H0_new
}

// ---------------- Mid layers: 1024 buckets, one wave per bucket, 4 buckets/block. ----
// Partial layout: P[d*1024 + src*4 + w] where d = dest block, src = source block,
// w = bucket-within-dest-block. Reads near-coalesced, writes quad-contiguous.
__global__ __launch_bounds__(256)
void mid_kernel(const float* __restrict__ Hl, const float* __restrict__ Sl,
                const float* __restrict__ thl, const float* __restrict__ Pin,
                int npart, float* __restrict__ Pout, float* __restrict__ outl,
                const float* __restrict__ precip)
{
    __shared__ float acc[1024];
    const int tid  = threadIdx.x;
    const int lane = tid & 63;
    const int w    = tid >> 6;                 // bucket within block
    const int b    = blockIdx.x * 4 + w;

#pragma unroll
    for (int r = 0; r < 4; ++r) acc[r * 256 + tid] = 0.0f;

    const float pb = precip[0] * (0.0625f / 1024.0f);   // exact: 2^-14 * precip
    const float H  = Hl[b];

    // prefetch this bucket's S row and theta row, transform to (e, c)
    const float2* S2   = (const float2*)Sl + (size_t)b * 1024;
    const float*  thrw = thl + (size_t)b * 1024;
    float e[16], cc[16];
#pragma unroll
    for (int c = 0; c < 16; ++c) {
        float2 s = S2[c * 64 + lane];
        float t  = thrw[c * 64 + lane];
        e[c]  = H - s.x;
        cc[c] = t * s.y * SQ2G;
    }

    // gather inflow partials: bucket b needs sum over src of Pin[blk*1024 + src*4 + w]
    float part = 0.0f;
    const float* prow = Pin + (size_t)blockIdx.x * 1024 + w;
#pragma unroll
    for (int k = 0; k < 4; ++k) {
        int src = k * 64 + lane;
        if (src < npart) part += prow[src * 4];
    }
    const float inflow = pb + wave_sum(part);

    __syncthreads();   // acc zero-init visible to all waves

    // spigot 0: H_eff = H + inflow
    float e0 = __shfl(e[0], 0), c0 = __shfl(cc[0], 0);
    float d0 = e0 + inflow;
    float q0 = (d0 > 0.0f) ? c0 * sqrtf(d0) : 0.0f;
    float cum = q0;
    if (lane == 0 && q0 != 0.0f) atomicAdd(&acc[0], q0);

    float qmine[16];
    drain<1>(e, cc, lane, cum, qmine);

#pragma unroll
    for (int c = 0; c < 16; ++c)
        if (qmine[c] != 0.0f) atomicAdd(&acc[c * 64 + lane], qmine[c]);

    if (lane == 0) outl[b] = (H - cum) + inflow;   // H_mid_new[l][b]

    __syncthreads();
#pragma unroll
    for (int r = 0; r < 4; ++r) {
        int i = r * 256 + tid;
        Pout[(i >> 2) * 1024 + blockIdx.x * 4 + (i & 3)] = acc[i];
    }
}

// ---------------- Last layer: 1024 buckets, 1 spigot each; wave-per-bucket gather. ---
__global__ __launch_bounds__(256)
void last_kernel(const float* __restrict__ Hlast, const float* __restrict__ Slast,
                 const float* __restrict__ thlast, const float* __restrict__ Pin,
                 const float* __restrict__ precip, float* __restrict__ out)
{
    const int lane = threadIdx.x & 63;
    const int w    = threadIdx.x >> 6;
    const int b    = blockIdx.x * 4 + w;
    const float pb = precip[0] * (0.0625f / 1024.0f);

    float part = 0.0f;
    const float* prow = Pin + (size_t)blockIdx.x * 1024 + w;
#pragma unroll
    for (int k = 0; k < 4; ++k) part += prow[(k * 64 + lane) * 4];
    float inflow = pb + wave_sum(part);

    if (lane == 0) {
        float H = Hlast[b];
        float2 s = ((const float2*)Slast)[b];
        float d = (H + inflow) - s.x;
        float q = (d > 0.0f) ? thlast[b] * sqrtf(19.6f * d) * s.y : 0.0f;
        out[1 + 14 * 1024 + b]        = (H - q) + inflow;   // H_last_new
        out[1 + 14 * 1024 + 1024 + b] = q;                  // q_last
    }
}

extern "C" void kernel_launch(void* const* d_in, const int* in_sizes, int n_in,
                              void* d_out, int out_size, void* d_ws, size_t ws_size,
                              hipStream_t stream)
{
    (void)in_sizes; (void)n_in; (void)out_size; (void)ws_size;
    const float* H0     = (const float*)d_in[0];
    const float* Hmid   = (const float*)d_in[1];
    const float* Hlast  = (const float*)d_in[2];
    const float* S0     = (const float*)d_in[3];
    const float* Smid   = (const float*)d_in[4];
    const float* Slast  = (const float*)d_in[5];
    const float* th0    = (const float*)d_in[6];
    const float* thmid  = (const float*)d_in[7];
    const float* thlast = (const float*)d_in[8];
    const float* precip = (const float*)d_in[9];
    float* out = (float*)d_out;
    float* PA  = (float*)d_ws;                 // 256 x 1024 partials (ping)
    float* PB  = PA + (size_t)256 * 1024;      // pong

    layer0_kernel<<<1, 64, 0, stream>>>(H0, S0, th0, precip, out, PA);

    float* cur = PA;
    float* nxt = PB;
    int npart = 1;                             // layer0 wrote src=0 only
    for (int l = 0; l < 14; ++l) {
        mid_kernel<<<256, 256, 0, stream>>>(Hmid + (size_t)l * 1024,
                                            Smid + (size_t)l * 1024 * 1024 * 2,
                                            thmid + (size_t)l * 1024 * 1024,
                                            cur, npart, nxt,
                                            out + 1 + (size_t)l * 1024,
                                            precip);
        float* t = cur; cur = nxt; nxt = t;
        npart = 256;
    }

    last_kernel<<<256, 256, 0, stream>>>(Hlast, Slast, thlast, cur, precip, out);
}